// Round 1
// baseline (42.156 us; speedup 1.0000x reference)
//
#include <hip/hip_runtime.h>

#define N_V 8192
#define NFACES 16384
#define NEDGES (NFACES * 6)
#define D 64
#define EPS 1e-7f
#define HASH_CAP 262144u   // power of 2, > 98304 max inserts -> probing terminates

// ---------------- column/feature totals: total[k] = sum_i input[i][k] ----------------
__global__ void total_sum_kernel(const float* __restrict__ input, float* __restrict__ total) {
    int col = threadIdx.x & 63;
    int rq  = threadIdx.x >> 6;            // 0..3
    int rowBase = blockIdx.x * 256;        // 32 blocks * 256 rows = 8192
    float s = 0.f;
    for (int r = rq; r < 256; r += 4)
        s += input[(size_t)(rowBase + r) * D + col];
    atomicAdd(&total[col], s);
}

// ---------------- per-edge: dedup + sparse accumulation ----------------
__global__ void edge_kernel(const int* __restrict__ faces,
                            const float* __restrict__ verts,
                            const float* __restrict__ input,
                            const float* __restrict__ sigma,
                            unsigned* __restrict__ htab,
                            float* __restrict__ rowacc,
                            float* __restrict__ colsum) {
    int e = blockIdx.x * blockDim.x + threadIdx.x;
    if (e >= NEDGES) return;
    int f = e / 6, s = e % 6;
    // halfedges (0,1),(0,2),(1,2) then reversed (1,0),(2,0),(2,1)
    const int p0[6] = {0, 0, 1, 1, 2, 2};
    const int p1[6] = {1, 2, 2, 0, 0, 1};
    int a = faces[f * 3 + p0[s]];   // src (row)
    int b = faces[f * 3 + p1[s]];   // dst (col)

    float dx = verts[a * 3 + 0] - verts[b * 3 + 0];
    float dy = verts[a * 3 + 1] - verts[b * 3 + 1];
    float dz = verts[a * 3 + 2] - verts[b * 3 + 2];
    float d2 = dx * dx + dy * dy + dz * dz;
    float sg = sigma[0];
    float w  = expf(-d2 / (sg * sg));
    float wp = fmaxf(w, EPS) - EPS;        // contribution above the EPS floor
    if (wp <= 0.f) return;                 // underflowed edge: identical to non-edge

    // exact dedup: reference scatter is .set(), duplicates count ONCE
    unsigned key = ((unsigned)a << 13) | (unsigned)b;
    unsigned h = (key * 2654435761u) & (HASH_CAP - 1u);
    while (true) {
        unsigned prev = atomicCAS(&htab[h], 0xFFFFFFFFu, key);
        if (prev == key) return;           // duplicate edge -> already counted
        if (prev == 0xFFFFFFFFu) break;    // newly inserted
        h = (h + 1u) & (HASH_CAP - 1u);
    }

    atomicAdd(&colsum[b], wp);
    const float* inb = input + (size_t)b * D;
    float* ra = rowacc + (size_t)a * D;
#pragma unroll
    for (int k = 0; k < D; ++k)
        atomicAdd(&ra[k], wp * inb[k]);
}

// ---------------- fused epilogue: out = in*fc^T + z*nfc^T + (fc_b+nfc_b) ----------------
// z[i] = dinv[i] * (EPS*total + rowacc[i]),  dinv[i] = 1/(n*EPS + colsum[i])
__global__ __launch_bounds__(256) void final_kernel(
        const float* __restrict__ input,
        const float* __restrict__ rowacc,
        const float* __restrict__ colsum,
        const float* __restrict__ total,
        const float* __restrict__ fc_w, const float* __restrict__ fc_b,
        const float* __restrict__ nfc_w, const float* __restrict__ nfc_b,
        float* __restrict__ out) {
    __shared__ float wfc[D][D + 1];   // +1 pad: lane o reads wfc[o][k] -> bank (o+k)%32
    __shared__ float wnf[D][D + 1];
    __shared__ float rin[4][D];
    __shared__ float zz[4][D];
    __shared__ float bias[D];
    __shared__ float etot[D];

    for (int i = threadIdx.x; i < D * D; i += 256) {
        wfc[i >> 6][i & 63] = fc_w[i];
        wnf[i >> 6][i & 63] = nfc_w[i];
    }
    if (threadIdx.x < D) {
        bias[threadIdx.x] = fc_b[threadIdx.x] + nfc_b[threadIdx.x];
        etot[threadIdx.x] = EPS * total[threadIdx.x];
    }
    __syncthreads();

    const int rl = threadIdx.x >> 6;   // row within 4-row group
    const int o  = threadIdx.x & 63;   // output feature
    const int rowsPerBlock = N_V / gridDim.x;
    const int row0 = blockIdx.x * rowsPerBlock;
    const float nEps = (float)N_V * EPS;

    for (int rr = 0; rr < rowsPerBlock; rr += 4) {
        int row = row0 + rr + rl;
        rin[rl][o] = input[(size_t)row * D + o];
        float dinv = 1.f / (nEps + colsum[row]);
        zz[rl][o] = dinv * (etot[o] + rowacc[(size_t)row * D + o]);
        __syncthreads();
        float acc = bias[o];
#pragma unroll
        for (int k = 0; k < D; ++k)
            acc += rin[rl][k] * wfc[o][k] + zz[rl][k] * wnf[o][k];
        out[(size_t)row * D + o] = acc;
        __syncthreads();
    }
}

extern "C" void kernel_launch(void* const* d_in, const int* in_sizes, int n_in,
                              void* d_out, int out_size, void* d_ws, size_t ws_size,
                              hipStream_t stream) {
    const float* input    = (const float*)d_in[0];
    // d_in[1] = A (unused), d_in[2] = Dinv (unused by reference)
    const float* vertices = (const float*)d_in[3];
    const int*   faces    = (const int*)d_in[4];
    const float* sigma    = (const float*)d_in[5];
    const float* fc_w     = (const float*)d_in[6];
    const float* fc_b     = (const float*)d_in[7];
    const float* nfc_w    = (const float*)d_in[8];
    const float* nfc_b    = (const float*)d_in[9];
    float* out = (float*)d_out;

    // workspace layout (4-byte units):
    // [htab: HASH_CAP u32][rowacc: N*64 f32][colsum: N f32][total: 64 f32]
    unsigned* htab = (unsigned*)d_ws;
    float* rowacc  = (float*)d_ws + HASH_CAP;
    float* colsum  = rowacc + (size_t)N_V * D;
    float* total   = colsum + N_V;

    // re-init scratch every call (harness poisons ws once, never restores)
    hipMemsetAsync(htab, 0xFF, HASH_CAP * sizeof(unsigned), stream);
    hipMemsetAsync(rowacc, 0, ((size_t)N_V * D + N_V + D) * sizeof(float), stream);

    total_sum_kernel<<<32, 256, 0, stream>>>(input, total);
    edge_kernel<<<(NEDGES + 255) / 256, 256, 0, stream>>>(faces, vertices, input, sigma,
                                                          htab, rowacc, colsum);
    final_kernel<<<256, 256, 0, stream>>>(input, rowacc, colsum, total,
                                          fc_w, fc_b, nfc_w, nfc_b, out);
}